// Round 17
// baseline (153.763 us; speedup 1.0000x reference)
//
#include <hip/hip_runtime.h>

// MultiHeadAttention: B=4, S=4096, D=256 (single head, fp32 in/out)
// R16 assembly + halved A-operand L3 traffic in qkv/oproj:
//   cvt_all -> qkv_gemm(128,6 x 512thr: 8 waves = 4 m-subs x 2 n-subs)
//   -> attn (R13: 8-wave 32q, fragment-order LDS, KVBLK=32 tri-buffer,
//      vmcnt(4), log2-domain softmax, defer-max, cvt_pk, KSPLIT=4)
//   -> combine -> oproj(128,2 x 512thr)

#define THR 8.0f   // log2-domain defer-max threshold

typedef __attribute__((ext_vector_type(8)))  short short8;
typedef __attribute__((ext_vector_type(4)))  short short4v;
typedef __attribute__((ext_vector_type(4)))  float f32x4;
typedef __attribute__((ext_vector_type(16))) float f32x16;
typedef __attribute__((ext_vector_type(4)))  float float4v;
typedef __attribute__((ext_vector_type(2)))  float float2v;

static constexpr int BB = 4, SS = 4096, DD = 256;
static constexpr int KSPLIT = 4;

// ws element offsets (shorts)
static constexpr size_t OFF_W1  = 0;
static constexpr size_t OFF_W2  = 196608;
static constexpr size_t OFF_Q   = 262144;
static constexpr size_t OFF_K   = 4456448;
static constexpr size_t OFF_VT  = 8650752;                // [B][D][Sperm]
static constexpr size_t OFF_XB  = 12845056;               // x bf16; reused as VAL
static constexpr size_t OFF_VAL = 12845056;
static constexpr size_t OFF_OP  = 17039360;               // partial O bf16
static constexpr size_t OFF_ML  = 17039360 + (size_t)KSPLIT * BB * SS * DD;
static constexpr size_t WS_NEED_SPLIT = (OFF_ML + (size_t)BB * SS * KSPLIT * 2) * 2;

__device__ __forceinline__ short f2bf(float f) {
    union { float f; unsigned u; } v; v.f = f;
    unsigned u = v.u;
    u += 0x7fffu + ((u >> 16) & 1u);
    return (short)(u >> 16);
}
__device__ __forceinline__ float bf2f(short s) {
    union { unsigned u; float f; } v; v.u = ((unsigned)(unsigned short)s) << 16;
    return v.f;
}
__device__ __forceinline__ void gload_lds16(const void* g, void* l) {
    __builtin_amdgcn_global_load_lds(
        (const __attribute__((address_space(1))) unsigned int*)g,
        (__attribute__((address_space(3))) unsigned int*)l, 16, 0, 0);
}

// ---------------- fp32 -> bf16 convert ----------------
__global__ __launch_bounds__(256) void cvt_all(
    const float* __restrict__ x, const float* __restrict__ w1,
    const float* __restrict__ w2, short* __restrict__ xb,
    short* __restrict__ w1b, short* __restrict__ w2b)
{
    const int n_x = (BB * SS * DD) / 4;
    const int n_1 = (3 * DD * DD) / 4;
    const int n_2 = (DD * DD) / 4;
    int i = blockIdx.x * 256 + threadIdx.x;
    if (i >= n_x + n_1 + n_2) return;
    const float* src; short* dst; int off;
    if (i < n_x)            { src = x;  dst = xb;  off = i; }
    else if (i < n_x + n_1) { src = w1; dst = w1b; off = i - n_x; }
    else                    { src = w2; dst = w2b; off = i - n_x - n_1; }
    float4v v = *(const float4v*)(src + 4 * (size_t)off);
    short4v o;
    o[0] = f2bf(v[0]); o[1] = f2bf(v[1]); o[2] = f2bf(v[2]); o[3] = f2bf(v[3]);
    *(short4v*)(dst + 4 * (size_t)off) = o;
}

// ---------------- QKV projection (8 waves: 4 m-subs x 2 n-subs) -------------
// grid(128,6) x 512thr. Block covers 128 rows x 128 cols; A rows read once
// per block (2nd n-sub hits L1/L2) -> A-L3-traffic halved vs (128,12)x256.
__global__ __launch_bounds__(512) void qkv_gemm(
    const short* __restrict__ xb, const short* __restrict__ wb,
    const float* __restrict__ bias,
    short* __restrict__ Qw, short* __restrict__ Kw, short* __restrict__ Vt)
{
    const int lane = threadIdx.x & 63;
    const int w    = threadIdx.x >> 6;
    const int ln = lane & 15, lg = lane >> 4;
    const int mbase = blockIdx.x * 128 + (w & 3) * 32;
    const int nbase = blockIdx.y * 128 + (w >> 2) * 64;

    f32x4 acc[2][4] = {};
    const short* arow0 = xb + (size_t)(mbase + ln) * DD + 8 * lg;
    const short* arow1 = arow0 + 16 * DD;
#pragma unroll
    for (int kk = 0; kk < 8; ++kk) {
        short8 a0 = *(const short8*)(arow0 + 32 * kk);
        short8 a1 = *(const short8*)(arow1 + 32 * kk);
#pragma unroll
        for (int nt = 0; nt < 4; ++nt) {
            short8 bf = *(const short8*)(wb + (size_t)(nbase + 16 * nt + ln) * DD + 32 * kk + 8 * lg);
            acc[0][nt] = __builtin_amdgcn_mfma_f32_16x16x32_bf16(a0, bf, acc[0][nt], 0, 0, 0);
            acc[1][nt] = __builtin_amdgcn_mfma_f32_16x16x32_bf16(a1, bf, acc[1][nt], 0, 0, 0);
        }
    }
#pragma unroll
    for (int mt = 0; mt < 2; ++mt) {
#pragma unroll
        for (int nt = 0; nt < 4; ++nt) {
            const int e = nbase + 16 * nt + ln;
            const float bv = bias[e];
            const int srow0 = mbase + mt * 16 + 4 * lg;
            const int b   = srow0 >> 12;
            const int si0 = srow0 & 4095;
            if (e < 256) {
#pragma unroll
                for (int r = 0; r < 4; ++r) {
                    float v = (acc[mt][nt][r] + bv) * 0.09016844005556021f;  // (1/16)*log2(e)
                    Qw[((size_t)b * SS + si0 + r) * DD + e] = f2bf(v);
                }
            } else if (e < 512) {
#pragma unroll
                for (int r = 0; r < 4; ++r)
                    Kw[((size_t)b * SS + si0 + r) * DD + (e - 256)] = f2bf(acc[mt][nt][r] + bv);
            } else {
                short4v st;
#pragma unroll
                for (int r = 0; r < 4; ++r) st[r] = f2bf(acc[mt][nt][r] + bv);
                const int sp = (si0 & ~12) | ((si0 & 4) << 1) | ((si0 & 8) >> 1);
                *(short4v*)(Vt + ((size_t)b * DD + (e - 512)) * SS + sp) = st;
            }
        }
    }
}

// ---------------- 8-wave split-K flash attention (R13, best measured) -------
template<int KSP>
__global__ __launch_bounds__(512, 2) void attn(
    const short* __restrict__ Qw, const short* __restrict__ Kw,
    const short* __restrict__ Vt, short* __restrict__ Opart,
    float* __restrict__ Ml, short* __restrict__ Val)
{
    constexpr int KCHUNK = SS / KSP;
    constexpr int NKB = KCHUNK / 32;
    extern __shared__ __align__(128) char smem[];   // 3 x (K 16KB | V 16KB)

    const int id = blockIdx.x;
    const int combo = id % (KSP * BB);
    const int qb    = id / (KSP * BB);
    const int ks = combo % KSP;
    const int b  = combo / KSP;
    const int t = threadIdx.x;
    const int lane = t & 63, w = t >> 6;
    const int lr = lane & 31, hi = lane >> 5;
    const int q0 = qb * 256 + w * 32;
    const int kbeg = ks * KCHUNK;

    const short* Qp = Qw + ((size_t)b * SS + q0 + lr) * DD + 8 * hi;
    short8 qf[16];
#pragma unroll
    for (int c = 0; c < 16; ++c) qf[c] = *(const short8*)(Qp + 16 * c);

    f32x16 o_acc[8] = {};
    float m_run = -1e30f, l_part = 0.f;

    const char* Kg0 = (const char*)(Kw + ((size_t)b * SS + kbeg) * DD);
    const char* Vg0 = (const char*)(Vt + (size_t)b * DD * SS) + 2 * kbeg;

    auto stage = [&](int buf, int kb) {
        char* base = smem + buf * 32768;
        const char* kg = Kg0 + (size_t)kb * 16384;
        const char* vg = Vg0 + (size_t)kb * 64;
#pragma unroll
        for (int i = 0; i < 4; ++i) {
            const int f = w * 4 + i;
            if (f < 16) {
                gload_lds16(kg + (size_t)lr * 512 + f * 32 + hi * 16,
                            base + f * 1024);
            } else {
                const int g = f - 16, s = g >> 3, dt = g & 7;
                gload_lds16(vg + (size_t)(dt * 32 + lr) * 8192 + s * 32 + hi * 16,
                            base + 16384 + g * 1024);
            }
        }
    };

    stage(0, 0);
    stage(1, 1);
    asm volatile("s_waitcnt vmcnt(4)" ::: "memory");
    __builtin_amdgcn_s_barrier();

    int cur = 0;
    for (int kb = 0; kb < NKB; ++kb) {
        const int nx2 = (cur + 2 >= 3) ? cur - 1 : cur + 2;
        if (kb + 2 < NKB) stage(nx2, kb + 2);

        const char* myK = smem + cur * 32768 + lane * 16;
        const char* myV = smem + cur * 32768 + 16384 + lane * 16;

        // QK^T: S^T[key][q] (scores in log2 units)
        f32x16 sacc = {};
        __builtin_amdgcn_s_setprio(1);
#pragma unroll
        for (int c = 0; c < 16; ++c) {
            short8 kf = *(const short8*)(myK + c * 1024);
            sacc = __builtin_amdgcn_mfma_f32_32x32x16_bf16(kf, qf[c], sacc, 0, 0, 0);
        }
        __builtin_amdgcn_s_setprio(0);

        // online softmax, log2 domain, defer-max
        float pm = sacc[0];
#pragma unroll
        for (int r = 1; r < 16; ++r) pm = fmaxf(pm, sacc[r]);
        pm = fmaxf(pm, __shfl_xor(pm, 32));
        if (__any(pm > m_run + THR)) {
            const float mnew = fmaxf(m_run, pm);
            const float corr = exp2f(m_run - mnew);
            m_run = mnew;
            l_part *= corr;
#pragma unroll
            for (int dt = 0; dt < 8; ++dt)
#pragma unroll
                for (int r = 0; r < 16; ++r) o_acc[dt][r] *= corr;
        }
        const float mref = m_run;
        float ps0 = 0.f, ps1 = 0.f;
#pragma unroll
        for (int r = 0; r < 16; ++r) {
            float p = exp2f(sacc[r] - mref);
            if (r & 1) ps1 += p; else ps0 += p;
            sacc[r] = p;
        }
        l_part += ps0 + ps1;

        // PV: O^T[d][q] += V^T[d][key] * P^T[key][q]
#pragma unroll
        for (int s = 0; s < 2; ++s) {
            union { short8 v; unsigned u[4]; } pb;
#pragma unroll
            for (int i = 0; i < 4; ++i)
                asm("v_cvt_pk_bf16_f32 %0, %1, %2"
                    : "=v"(pb.u[i])
                    : "v"(sacc[8 * s + 2 * i]), "v"(sacc[8 * s + 2 * i + 1]));
            __builtin_amdgcn_s_setprio(1);
#pragma unroll
            for (int dt = 0; dt < 8; ++dt) {
                short8 vf = *(const short8*)(myV + (s * 8 + dt) * 1024);
                o_acc[dt] = __builtin_amdgcn_mfma_f32_32x32x16_bf16(vf, pb.v, o_acc[dt], 0, 0, 0);
            }
            __builtin_amdgcn_s_setprio(0);
        }

        if (kb + 1 < NKB) {
            if (kb + 2 < NKB) asm volatile("s_waitcnt vmcnt(4)" ::: "memory");
            else              asm volatile("s_waitcnt vmcnt(0)" ::: "memory");
            __builtin_amdgcn_s_barrier();
        }
        cur = (cur + 1 >= 3) ? 0 : cur + 1;
    }

    float lt = l_part + __shfl_xor(l_part, 32);
    const float inv = 1.0f / lt;
    const size_t row = (size_t)b * SS + q0 + lr;
    short* vo = (KSP == 1 ? Val : Opart + (size_t)ks * (BB * SS) * DD) + row * DD;
#pragma unroll
    for (int dt = 0; dt < 8; ++dt)
#pragma unroll
        for (int g = 0; g < 4; ++g) {
            short4v st;
#pragma unroll
            for (int i = 0; i < 4; ++i) st[i] = f2bf(o_acc[dt][4 * g + i] * inv);
            *(short4v*)(vo + dt * 32 + 8 * g + 4 * hi) = st;
        }
    if (KSP > 1 && hi == 0) {
        float2v ml; ml[0] = m_run; ml[1] = lt;   // m in log2 units
        *(float2v*)(Ml + (row * KSP + ks) * 2) = ml;
    }
}

// ---------------- split combine (vectorized x4, log2 domain) ----------------
__global__ __launch_bounds__(256) void combine(
    const short* __restrict__ Opart, const float* __restrict__ Ml,
    short* __restrict__ Val)
{
    const int idx = blockIdx.x * 256 + threadIdx.x;
    const int row = idx >> 6;
    const int d4 = (idx & 63) * 4;
    float m[KSPLIT], l[KSPLIT];
    float M = -1e30f;
#pragma unroll
    for (int i = 0; i < KSPLIT; ++i) {
        float2v v = *(const float2v*)(Ml + ((size_t)row * KSPLIT + i) * 2);
        m[i] = v[0]; l[i] = v[1];
        M = fmaxf(M, m[i]);
    }
    float wsum = 0.f;
    f32x4 acc = {};
#pragma unroll
    for (int i = 0; i < KSPLIT; ++i) {
        float wgt = l[i] * exp2f(m[i] - M);
        wsum += wgt;
        short4v v = *(const short4v*)(Opart + (size_t)i * (BB * SS * DD) + (size_t)row * DD + d4);
#pragma unroll
        for (int j = 0; j < 4; ++j) acc[j] += wgt * bf2f(v[j]);
    }
    const float inv = 1.0f / wsum;
    short4v st;
#pragma unroll
    for (int j = 0; j < 4; ++j) st[j] = f2bf(acc[j] * inv);
    *(short4v*)(Val + (size_t)row * DD + d4) = st;
}

// ---------------- out projection (8 waves: 4 m-subs x 2 n-subs) -------------
// grid(128,2) x 512thr: Val rows read once per block -> A-traffic halved.
__global__ __launch_bounds__(512) void oproj_gemm(
    const short* __restrict__ vb, const short* __restrict__ wb,
    const float* __restrict__ bias, float* __restrict__ out)
{
    const int lane = threadIdx.x & 63;
    const int w    = threadIdx.x >> 6;
    const int ln = lane & 15, lg = lane >> 4;
    const int mbase = blockIdx.x * 128 + (w & 3) * 32;
    const int nbase = blockIdx.y * 128 + (w >> 2) * 64;

    f32x4 acc[2][4] = {};
    const short* arow0 = vb + (size_t)(mbase + ln) * DD + 8 * lg;
    const short* arow1 = arow0 + 16 * DD;
#pragma unroll
    for (int kk = 0; kk < 8; ++kk) {
        short8 a0 = *(const short8*)(arow0 + 32 * kk);
        short8 a1 = *(const short8*)(arow1 + 32 * kk);
#pragma unroll
        for (int nt = 0; nt < 4; ++nt) {
            short8 bf = *(const short8*)(wb + (size_t)(nbase + 16 * nt + ln) * DD + 32 * kk + 8 * lg);
            acc[0][nt] = __builtin_amdgcn_mfma_f32_16x16x32_bf16(a0, bf, acc[0][nt], 0, 0, 0);
            acc[1][nt] = __builtin_amdgcn_mfma_f32_16x16x32_bf16(a1, bf, acc[1][nt], 0, 0, 0);
        }
    }
#pragma unroll
    for (int mt = 0; mt < 2; ++mt)
#pragma unroll
        for (int nt = 0; nt < 4; ++nt) {
            const int e = nbase + 16 * nt + ln;
            const float bv = bias[e];
#pragma unroll
            for (int r = 0; r < 4; ++r)
                out[(size_t)(mbase + mt * 16 + 4 * lg + r) * DD + e] = acc[mt][nt][r] + bv;
        }
}

extern "C" void kernel_launch(void* const* d_in, const int* in_sizes, int n_in,
                              void* d_out, int out_size, void* d_ws, size_t ws_size,
                              hipStream_t stream) {
    const float* x    = (const float*)d_in[0];
    const float* Wqkv = (const float*)d_in[1];
    const float* bqkv = (const float*)d_in[2];
    const float* Wo   = (const float*)d_in[3];
    const float* bo   = (const float*)d_in[4];
    float* out = (float*)d_out;
    short* ws  = (short*)d_ws;

    short* w1b = ws + OFF_W1;
    short* w2b = ws + OFF_W2;
    short* Qw  = ws + OFF_Q;
    short* Kw  = ws + OFF_K;
    short* Vt  = ws + OFF_VT;
    short* xb  = ws + OFF_XB;
    short* Val = ws + OFF_VAL;
    short* Opart = ws + OFF_OP;
    float* Ml  = (float*)(ws + OFF_ML);

    cvt_all<<<4352, 256, 0, stream>>>(x, Wqkv, Wo, xb, w1b, w2b);
    qkv_gemm<<<dim3(128, 6), 512, 0, stream>>>(xb, w1b, bqkv, Qw, Kw, Vt);

    constexpr size_t SMEM = 98304;
    if (ws_size >= WS_NEED_SPLIT) {
        (void)hipFuncSetAttribute((const void*)attn<KSPLIT>,
                                  hipFuncAttributeMaxDynamicSharedMemorySize, SMEM);
        attn<KSPLIT><<<16 * KSPLIT * BB, 512, SMEM, stream>>>(Qw, Kw, Vt, Opart, Ml, nullptr);
        combine<<<4096, 256, 0, stream>>>(Opart, Ml, Val);
    } else {
        (void)hipFuncSetAttribute((const void*)attn<1>,
                                  hipFuncAttributeMaxDynamicSharedMemorySize, SMEM);
        attn<1><<<16 * BB, 512, SMEM, stream>>>(Qw, Kw, Vt, nullptr, nullptr, Val);
    }
    oproj_gemm<<<dim3(128, 2), 512, 0, stream>>>(Val, w2b, bo, out);
}

// Round 18
// 151.416 us; speedup vs baseline: 1.0155x; 1.0155x over previous
//
#include <hip/hip_runtime.h>

// MultiHeadAttention: B=4, S=4096, D=256 (single head, fp32 in/out)
// R17 assembly; attn variant: 4-buffer LDS, continuous per-tile staging,
// barrier every 2 tiles (isolates barrier-count from R11's bursty staging).

#define THR 8.0f   // log2-domain defer-max threshold

typedef __attribute__((ext_vector_type(8)))  short short8;
typedef __attribute__((ext_vector_type(4)))  short short4v;
typedef __attribute__((ext_vector_type(4)))  float f32x4;
typedef __attribute__((ext_vector_type(16))) float f32x16;
typedef __attribute__((ext_vector_type(4)))  float float4v;
typedef __attribute__((ext_vector_type(2)))  float float2v;

static constexpr int BB = 4, SS = 4096, DD = 256;
static constexpr int KSPLIT = 4;

// ws element offsets (shorts)
static constexpr size_t OFF_W1  = 0;
static constexpr size_t OFF_W2  = 196608;
static constexpr size_t OFF_Q   = 262144;
static constexpr size_t OFF_K   = 4456448;
static constexpr size_t OFF_VT  = 8650752;                // [B][D][Sperm]
static constexpr size_t OFF_XB  = 12845056;               // x bf16; reused as VAL
static constexpr size_t OFF_VAL = 12845056;
static constexpr size_t OFF_OP  = 17039360;               // partial O bf16
static constexpr size_t OFF_ML  = 17039360 + (size_t)KSPLIT * BB * SS * DD;
static constexpr size_t WS_NEED_SPLIT = (OFF_ML + (size_t)BB * SS * KSPLIT * 2) * 2;

__device__ __forceinline__ short f2bf(float f) {
    union { float f; unsigned u; } v; v.f = f;
    unsigned u = v.u;
    u += 0x7fffu + ((u >> 16) & 1u);
    return (short)(u >> 16);
}
__device__ __forceinline__ float bf2f(short s) {
    union { unsigned u; float f; } v; v.u = ((unsigned)(unsigned short)s) << 16;
    return v.f;
}
__device__ __forceinline__ void gload_lds16(const void* g, void* l) {
    __builtin_amdgcn_global_load_lds(
        (const __attribute__((address_space(1))) unsigned int*)g,
        (__attribute__((address_space(3))) unsigned int*)l, 16, 0, 0);
}

// ---------------- fp32 -> bf16 convert ----------------
__global__ __launch_bounds__(256) void cvt_all(
    const float* __restrict__ x, const float* __restrict__ w1,
    const float* __restrict__ w2, short* __restrict__ xb,
    short* __restrict__ w1b, short* __restrict__ w2b)
{
    const int n_x = (BB * SS * DD) / 4;
    const int n_1 = (3 * DD * DD) / 4;
    const int n_2 = (DD * DD) / 4;
    int i = blockIdx.x * 256 + threadIdx.x;
    if (i >= n_x + n_1 + n_2) return;
    const float* src; short* dst; int off;
    if (i < n_x)            { src = x;  dst = xb;  off = i; }
    else if (i < n_x + n_1) { src = w1; dst = w1b; off = i - n_x; }
    else                    { src = w2; dst = w2b; off = i - n_x - n_1; }
    float4v v = *(const float4v*)(src + 4 * (size_t)off);
    short4v o;
    o[0] = f2bf(v[0]); o[1] = f2bf(v[1]); o[2] = f2bf(v[2]); o[3] = f2bf(v[3]);
    *(short4v*)(dst + 4 * (size_t)off) = o;
}

// ---------------- QKV projection (8 waves: 4 m-subs x 2 n-subs) -------------
__global__ __launch_bounds__(512) void qkv_gemm(
    const short* __restrict__ xb, const short* __restrict__ wb,
    const float* __restrict__ bias,
    short* __restrict__ Qw, short* __restrict__ Kw, short* __restrict__ Vt)
{
    const int lane = threadIdx.x & 63;
    const int w    = threadIdx.x >> 6;
    const int ln = lane & 15, lg = lane >> 4;
    const int mbase = blockIdx.x * 128 + (w & 3) * 32;
    const int nbase = blockIdx.y * 128 + (w >> 2) * 64;

    f32x4 acc[2][4] = {};
    const short* arow0 = xb + (size_t)(mbase + ln) * DD + 8 * lg;
    const short* arow1 = arow0 + 16 * DD;
#pragma unroll
    for (int kk = 0; kk < 8; ++kk) {
        short8 a0 = *(const short8*)(arow0 + 32 * kk);
        short8 a1 = *(const short8*)(arow1 + 32 * kk);
#pragma unroll
        for (int nt = 0; nt < 4; ++nt) {
            short8 bf = *(const short8*)(wb + (size_t)(nbase + 16 * nt + ln) * DD + 32 * kk + 8 * lg);
            acc[0][nt] = __builtin_amdgcn_mfma_f32_16x16x32_bf16(a0, bf, acc[0][nt], 0, 0, 0);
            acc[1][nt] = __builtin_amdgcn_mfma_f32_16x16x32_bf16(a1, bf, acc[1][nt], 0, 0, 0);
        }
    }
#pragma unroll
    for (int mt = 0; mt < 2; ++mt) {
#pragma unroll
        for (int nt = 0; nt < 4; ++nt) {
            const int e = nbase + 16 * nt + ln;
            const float bv = bias[e];
            const int srow0 = mbase + mt * 16 + 4 * lg;
            const int b   = srow0 >> 12;
            const int si0 = srow0 & 4095;
            if (e < 256) {
#pragma unroll
                for (int r = 0; r < 4; ++r) {
                    float v = (acc[mt][nt][r] + bv) * 0.09016844005556021f;  // (1/16)*log2(e)
                    Qw[((size_t)b * SS + si0 + r) * DD + e] = f2bf(v);
                }
            } else if (e < 512) {
#pragma unroll
                for (int r = 0; r < 4; ++r)
                    Kw[((size_t)b * SS + si0 + r) * DD + (e - 256)] = f2bf(acc[mt][nt][r] + bv);
            } else {
                short4v st;
#pragma unroll
                for (int r = 0; r < 4; ++r) st[r] = f2bf(acc[mt][nt][r] + bv);
                const int sp = (si0 & ~12) | ((si0 & 4) << 1) | ((si0 & 8) >> 1);
                *(short4v*)(Vt + ((size_t)b * DD + (e - 512)) * SS + sp) = st;
            }
        }
    }
}

// ---------------- 8-wave split-K flash attention ----------------
// R13 body; 4-buffer LDS, continuous per-tile staging (stage kb+2 each
// iteration), barrier only every 2nd tile. At each barrier all in-flight
// loads are >= half-interval old -> vmcnt(0) is free; buffer reuse distance
// 4 tiles vs max 2-tile skew -> race-free.
template<int KSP>
__global__ __launch_bounds__(512, 2) void attn(
    const short* __restrict__ Qw, const short* __restrict__ Kw,
    const short* __restrict__ Vt, short* __restrict__ Opart,
    float* __restrict__ Ml, short* __restrict__ Val)
{
    constexpr int KCHUNK = SS / KSP;
    constexpr int NKB = KCHUNK / 32;
    extern __shared__ __align__(128) char smem[];   // 4 x (K 16KB | V 16KB)

    const int id = blockIdx.x;
    const int combo = id % (KSP * BB);
    const int qb    = id / (KSP * BB);
    const int ks = combo % KSP;
    const int b  = combo / KSP;
    const int t = threadIdx.x;
    const int lane = t & 63, w = t >> 6;
    const int lr = lane & 31, hi = lane >> 5;
    const int q0 = qb * 256 + w * 32;
    const int kbeg = ks * KCHUNK;

    const short* Qp = Qw + ((size_t)b * SS + q0 + lr) * DD + 8 * hi;
    short8 qf[16];
#pragma unroll
    for (int c = 0; c < 16; ++c) qf[c] = *(const short8*)(Qp + 16 * c);

    f32x16 o_acc[8] = {};
    float m_run = -1e30f, l_part = 0.f;

    const char* Kg0 = (const char*)(Kw + ((size_t)b * SS + kbeg) * DD);
    const char* Vg0 = (const char*)(Vt + (size_t)b * DD * SS) + 2 * kbeg;

    auto stage = [&](int buf, int kb) {
        char* base = smem + buf * 32768;
        const char* kg = Kg0 + (size_t)kb * 16384;
        const char* vg = Vg0 + (size_t)kb * 64;
#pragma unroll
        for (int i = 0; i < 4; ++i) {
            const int f = w * 4 + i;
            if (f < 16) {
                gload_lds16(kg + (size_t)lr * 512 + f * 32 + hi * 16,
                            base + f * 1024);
            } else {
                const int g = f - 16, s = g >> 3, dt = g & 7;
                gload_lds16(vg + (size_t)(dt * 32 + lr) * 8192 + s * 32 + hi * 16,
                            base + 16384 + g * 1024);
            }
        }
    };

    stage(0, 0);
    stage(1, 1);
    asm volatile("s_waitcnt vmcnt(0)" ::: "memory");
    __builtin_amdgcn_s_barrier();

    for (int kb = 0; kb < NKB; ++kb) {
        if (kb + 2 < NKB) stage((kb + 2) & 3, kb + 2);

        const char* myK = smem + (kb & 3) * 32768 + lane * 16;
        const char* myV = smem + (kb & 3) * 32768 + 16384 + lane * 16;

        // QK^T: S^T[key][q] (scores in log2 units)
        f32x16 sacc = {};
        __builtin_amdgcn_s_setprio(1);
#pragma unroll
        for (int c = 0; c < 16; ++c) {
            short8 kf = *(const short8*)(myK + c * 1024);
            sacc = __builtin_amdgcn_mfma_f32_32x32x16_bf16(kf, qf[c], sacc, 0, 0, 0);
        }
        __builtin_amdgcn_s_setprio(0);

        // online softmax, log2 domain, defer-max
        float pm = sacc[0];
#pragma unroll
        for (int r = 1; r < 16; ++r) pm = fmaxf(pm, sacc[r]);
        pm = fmaxf(pm, __shfl_xor(pm, 32));
        if (__any(pm > m_run + THR)) {
            const float mnew = fmaxf(m_run, pm);
            const float corr = exp2f(m_run - mnew);
            m_run = mnew;
            l_part *= corr;
#pragma unroll
            for (int dt = 0; dt < 8; ++dt)
#pragma unroll
                for (int r = 0; r < 16; ++r) o_acc[dt][r] *= corr;
        }
        const float mref = m_run;
        float ps0 = 0.f, ps1 = 0.f;
#pragma unroll
        for (int r = 0; r < 16; ++r) {
            float p = exp2f(sacc[r] - mref);
            if (r & 1) ps1 += p; else ps0 += p;
            sacc[r] = p;
        }
        l_part += ps0 + ps1;

        // PV: O^T[d][q] += V^T[d][key] * P^T[key][q]
#pragma unroll
        for (int s = 0; s < 2; ++s) {
            union { short8 v; unsigned u[4]; } pb;
#pragma unroll
            for (int i = 0; i < 4; ++i)
                asm("v_cvt_pk_bf16_f32 %0, %1, %2"
                    : "=v"(pb.u[i])
                    : "v"(sacc[8 * s + 2 * i]), "v"(sacc[8 * s + 2 * i + 1]));
            __builtin_amdgcn_s_setprio(1);
#pragma unroll
            for (int dt = 0; dt < 8; ++dt) {
                short8 vf = *(const short8*)(myV + (s * 8 + dt) * 1024);
                o_acc[dt] = __builtin_amdgcn_mfma_f32_32x32x16_bf16(vf, pb.v, o_acc[dt], 0, 0, 0);
            }
            __builtin_amdgcn_s_setprio(0);
        }

        // barrier every 2nd tile only
        if ((kb & 1) && (kb + 1 < NKB)) {
            asm volatile("s_waitcnt vmcnt(0)" ::: "memory");
            __builtin_amdgcn_s_barrier();
        }
    }

    float lt = l_part + __shfl_xor(l_part, 32);
    const float inv = 1.0f / lt;
    const size_t row = (size_t)b * SS + q0 + lr;
    short* vo = (KSP == 1 ? Val : Opart + (size_t)ks * (BB * SS) * DD) + row * DD;
#pragma unroll
    for (int dt = 0; dt < 8; ++dt)
#pragma unroll
        for (int g = 0; g < 4; ++g) {
            short4v st;
#pragma unroll
            for (int i = 0; i < 4; ++i) st[i] = f2bf(o_acc[dt][4 * g + i] * inv);
            *(short4v*)(vo + dt * 32 + 8 * g + 4 * hi) = st;
        }
    if (KSP > 1 && hi == 0) {
        float2v ml; ml[0] = m_run; ml[1] = lt;   // m in log2 units
        *(float2v*)(Ml + (row * KSP + ks) * 2) = ml;
    }
}

// ---------------- split combine (vectorized x4, log2 domain) ----------------
__global__ __launch_bounds__(256) void combine(
    const short* __restrict__ Opart, const float* __restrict__ Ml,
    short* __restrict__ Val)
{
    const int idx = blockIdx.x * 256 + threadIdx.x;
    const int row = idx >> 6;
    const int d4 = (idx & 63) * 4;
    float m[KSPLIT], l[KSPLIT];
    float M = -1e30f;
#pragma unroll
    for (int i = 0; i < KSPLIT; ++i) {
        float2v v = *(const float2v*)(Ml + ((size_t)row * KSPLIT + i) * 2);
        m[i] = v[0]; l[i] = v[1];
        M = fmaxf(M, m[i]);
    }
    float wsum = 0.f;
    f32x4 acc = {};
#pragma unroll
    for (int i = 0; i < KSPLIT; ++i) {
        float wgt = l[i] * exp2f(m[i] - M);
        wsum += wgt;
        short4v v = *(const short4v*)(Opart + (size_t)i * (BB * SS * DD) + (size_t)row * DD + d4);
#pragma unroll
        for (int j = 0; j < 4; ++j) acc[j] += wgt * bf2f(v[j]);
    }
    const float inv = 1.0f / wsum;
    short4v st;
#pragma unroll
    for (int j = 0; j < 4; ++j) st[j] = f2bf(acc[j] * inv);
    *(short4v*)(Val + (size_t)row * DD + d4) = st;
}

// ---------------- out projection (8 waves: 4 m-subs x 2 n-subs) -------------
__global__ __launch_bounds__(512) void oproj_gemm(
    const short* __restrict__ vb, const short* __restrict__ wb,
    const float* __restrict__ bias, float* __restrict__ out)
{
    const int lane = threadIdx.x & 63;
    const int w    = threadIdx.x >> 6;
    const int ln = lane & 15, lg = lane >> 4;
    const int mbase = blockIdx.x * 128 + (w & 3) * 32;
    const int nbase = blockIdx.y * 128 + (w >> 2) * 64;

    f32x4 acc[2][4] = {};
    const short* arow0 = vb + (size_t)(mbase + ln) * DD + 8 * lg;
    const short* arow1 = arow0 + 16 * DD;
#pragma unroll
    for (int kk = 0; kk < 8; ++kk) {
        short8 a0 = *(const short8*)(arow0 + 32 * kk);
        short8 a1 = *(const short8*)(arow1 + 32 * kk);
#pragma unroll
        for (int nt = 0; nt < 4; ++nt) {
            short8 bf = *(const short8*)(wb + (size_t)(nbase + 16 * nt + ln) * DD + 32 * kk + 8 * lg);
            acc[0][nt] = __builtin_amdgcn_mfma_f32_16x16x32_bf16(a0, bf, acc[0][nt], 0, 0, 0);
            acc[1][nt] = __builtin_amdgcn_mfma_f32_16x16x32_bf16(a1, bf, acc[1][nt], 0, 0, 0);
        }
    }
#pragma unroll
    for (int mt = 0; mt < 2; ++mt)
#pragma unroll
        for (int nt = 0; nt < 4; ++nt) {
            const int e = nbase + 16 * nt + ln;
            const float bv = bias[e];
#pragma unroll
            for (int r = 0; r < 4; ++r)
                out[(size_t)(mbase + mt * 16 + 4 * lg + r) * DD + e] = acc[mt][nt][r] + bv;
        }
}

extern "C" void kernel_launch(void* const* d_in, const int* in_sizes, int n_in,
                              void* d_out, int out_size, void* d_ws, size_t ws_size,
                              hipStream_t stream) {
    const float* x    = (const float*)d_in[0];
    const float* Wqkv = (const float*)d_in[1];
    const float* bqkv = (const float*)d_in[2];
    const float* Wo   = (const float*)d_in[3];
    const float* bo   = (const float*)d_in[4];
    float* out = (float*)d_out;
    short* ws  = (short*)d_ws;

    short* w1b = ws + OFF_W1;
    short* w2b = ws + OFF_W2;
    short* Qw  = ws + OFF_Q;
    short* Kw  = ws + OFF_K;
    short* Vt  = ws + OFF_VT;
    short* xb  = ws + OFF_XB;
    short* Val = ws + OFF_VAL;
    short* Opart = ws + OFF_OP;
    float* Ml  = (float*)(ws + OFF_ML);

    cvt_all<<<4352, 256, 0, stream>>>(x, Wqkv, Wo, xb, w1b, w2b);
    qkv_gemm<<<dim3(128, 6), 512, 0, stream>>>(xb, w1b, bqkv, Qw, Kw, Vt);

    constexpr size_t SMEM = 131072;
    if (ws_size >= WS_NEED_SPLIT) {
        (void)hipFuncSetAttribute((const void*)attn<KSPLIT>,
                                  hipFuncAttributeMaxDynamicSharedMemorySize, SMEM);
        attn<KSPLIT><<<16 * KSPLIT * BB, 512, SMEM, stream>>>(Qw, Kw, Vt, Opart, Ml, nullptr);
        combine<<<4096, 256, 0, stream>>>(Opart, Ml, Val);
    } else {
        (void)hipFuncSetAttribute((const void*)attn<1>,
                                  hipFuncAttributeMaxDynamicSharedMemorySize, SMEM);
        attn<1><<<16 * BB, 512, SMEM, stream>>>(Qw, Kw, Vt, nullptr, nullptr, Val);
    }
    oproj_gemm<<<dim3(128, 2), 512, 0, stream>>>(Val, w2b, bo, out);
}